// Round 1
// baseline (430.047 us; speedup 1.0000x reference)
//
#include <hip/hip_runtime.h>
#include <hip/hip_bf16.h>

#define DIMD 512
#define NEXP 8
#define HIDN 2048
#define NTOK 4096
#define NASG 8192
#define M_BLK 32
#define HCHK 128

typedef short bf16x8 __attribute__((ext_vector_type(8)));
typedef float f32x4 __attribute__((ext_vector_type(4)));

__device__ inline unsigned short f2bf(float f) {
  __hip_bfloat16 h = __float2bfloat16(f);
  return __builtin_bit_cast(unsigned short, h);
}

// ---------- x -> bf16 ----------
__global__ __launch_bounds__(256) void cvt_x_kernel(const float* __restrict__ x,
                                                    unsigned short* __restrict__ xb) {
  int i = (blockIdx.x * 256 + threadIdx.x) * 8;
  float4 v0 = *reinterpret_cast<const float4*>(x + i);
  float4 v1 = *reinterpret_cast<const float4*>(x + i + 4);
  uint4 p;
  p.x = (unsigned)f2bf(v0.x) | ((unsigned)f2bf(v0.y) << 16);
  p.y = (unsigned)f2bf(v0.z) | ((unsigned)f2bf(v0.w) << 16);
  p.z = (unsigned)f2bf(v1.x) | ((unsigned)f2bf(v1.y) << 16);
  p.w = (unsigned)f2bf(v1.z) | ((unsigned)f2bf(v1.w) << 16);
  *reinterpret_cast<uint4*>(xb + i) = p;
}

// ---------- W [E][R][C] fp32 -> WT [E][C][R] bf16 (tiled transpose) ----------
__global__ __launch_bounds__(256) void transpose_w_kernel(const float* __restrict__ src,
                                                          unsigned short* __restrict__ dst,
                                                          int R, int C) {
  __shared__ float tile[64][65];
  int e = blockIdx.z;
  int c0 = blockIdx.x * 64, r0 = blockIdx.y * 64;
  const float* s = src + (size_t)e * R * C;
  unsigned short* d = dst + (size_t)e * R * C;
  for (int i = threadIdx.x; i < 4096; i += 256) {
    int r = i >> 6, c = i & 63;
    tile[r][c] = s[(size_t)(r0 + r) * C + (c0 + c)];
  }
  __syncthreads();
  for (int i = threadIdx.x; i < 4096; i += 256) {
    int c = i >> 6, r = i & 63;
    d[(size_t)(c0 + c) * R + (r0 + r)] = f2bf(tile[r][c]);
  }
}

// ---------- router: logits, softmax, top-2, renorm, counts ----------
__global__ __launch_bounds__(256) void router_kernel(const float* __restrict__ x,
                                                     const float* __restrict__ Wr,
                                                     const float* __restrict__ br,
                                                     int* __restrict__ cnt,
                                                     int* __restrict__ tidx,
                                                     float* __restrict__ tw) {
  int lane = threadIdx.x & 63;
  int n = blockIdx.x * 4 + (threadIdx.x >> 6);
  const float* xr = x + (size_t)n * DIMD;
  float acc[NEXP];
#pragma unroll
  for (int e = 0; e < NEXP; ++e) acc[e] = 0.f;
  for (int d = lane; d < DIMD; d += 64) {
    float xv = xr[d];
    const float* wr = Wr + (size_t)d * NEXP;
#pragma unroll
    for (int e = 0; e < NEXP; ++e) acc[e] += xv * wr[e];
  }
#pragma unroll
  for (int e = 0; e < NEXP; ++e) {
    float v = acc[e];
#pragma unroll
    for (int off = 32; off > 0; off >>= 1) v += __shfl_xor(v, off, 64);
    acc[e] = v + br[e];
  }
  if (lane == 0) {
    float m = acc[0];
    for (int e = 1; e < NEXP; ++e) m = fmaxf(m, acc[e]);
    float p[NEXP], s = 0.f;
    for (int e = 0; e < NEXP; ++e) { p[e] = expf(acc[e] - m); s += p[e]; }
    float inv = 1.f / s;
    for (int e = 0; e < NEXP; ++e) p[e] *= inv;
    int i0 = 0; float p0 = p[0];
    for (int e = 1; e < NEXP; ++e) if (p[e] > p0) { p0 = p[e]; i0 = e; }
    int i1 = (i0 == 0) ? 1 : 0; float p1 = p[i1];
    for (int e = 0; e < NEXP; ++e) if (e != i0 && p[e] > p1) { p1 = p[e]; i1 = e; }
    // reference renormalizes by softmax over the top-2 *probabilities*
    float t = expf(p1 - p0);
    float w0 = 1.f / (1.f + t);
    tidx[2 * n] = i0; tidx[2 * n + 1] = i1;
    tw[2 * n] = w0; tw[2 * n + 1] = t * w0;
    atomicAdd(&cnt[i0], 1);
    atomicAdd(&cnt[i1], 1);
  }
}

// ---------- offsets + lb_loss/load tail ----------
__global__ void finalize_kernel(const int* __restrict__ cnt, int* __restrict__ off,
                                int* __restrict__ cur, float* __restrict__ out_tail) {
  if (threadIdx.x == 0) {
    int o = 0;
    float lb = 0.f;
    for (int e = 0; e < NEXP; ++e) {
      off[e] = o; o += cnt[e];
      float l = (float)cnt[e] / (float)NASG;
      out_tail[1 + e] = l;
      float dd = l - 0.125f;
      lb += dd * dd;
      cur[e] = 0;
    }
    off[NEXP] = o;
    out_tail[0] = lb;
  }
}

// ---------- scatter assignment ids into per-expert lists ----------
__global__ __launch_bounds__(256) void scatter_kernel(const int* __restrict__ tidx,
                                                      const int* __restrict__ off,
                                                      int* __restrict__ cur,
                                                      int* __restrict__ list) {
  int a = blockIdx.x * 256 + threadIdx.x;
  if (a < NASG) {
    int e = tidx[a];
    int pos = off[e] + atomicAdd(&cur[e], 1);
    list[pos] = a;
  }
}

// ---------- grouped expert MLP: Yw[a] = w_a * (gelu(x W1 + b1) W2 + b2) ----------
__global__ __launch_bounds__(256, 2) void mlp_kernel(
    const unsigned short* __restrict__ xb,
    const unsigned short* __restrict__ w1t,   // [E][HIDN][DIMD] bf16 (W1 transposed)
    const unsigned short* __restrict__ w2t,   // [E][DIMD][HIDN] bf16 (W2 transposed)
    const float* __restrict__ b1,
    const float* __restrict__ b2,
    const int* __restrict__ off,
    const int* __restrict__ list,
    const float* __restrict__ tw,
    float* __restrict__ Yw) {
  int e = blockIdx.x;                       // bid%8 == expert -> XCD-pinned L2 reuse
  int cnt_e = off[e + 1] - off[e];
  int r0 = blockIdx.y * M_BLK;
  if (r0 >= cnt_e) return;
  int nr = cnt_e - r0; if (nr > M_BLK) nr = M_BLK;

  __shared__ unsigned short Xs[M_BLK][DIMD];   // 32 KB, XOR-swizzled rows
  __shared__ unsigned short Hs[M_BLK][HCHK];   // 8 KB, XOR-swizzled rows
  __shared__ int As[M_BLK];
  __shared__ float Wls[M_BLK];

  int tid = threadIdx.x;
  int wv = tid >> 6, lane = tid & 63;

  if (tid < M_BLK) {
    int a = -1; float w = 0.f;
    if (tid < nr) { a = list[off[e] + r0 + tid]; w = tw[a]; }
    As[tid] = a; Wls[tid] = w;
  }
  __syncthreads();

  char* XsB = (char*)Xs;
  char* HsB = (char*)Hs;

  // stage X rows (gathered by token) into swizzled LDS
  for (int u = tid; u < M_BLK * DIMD / 8; u += 256) {
    int row = u >> 6, cu = u & 63;
    uint4 val = make_uint4(0u, 0u, 0u, 0u);
    int a = As[row];
    if (a >= 0) {
      int tok = a >> 1;
      val = *reinterpret_cast<const uint4*>(xb + (size_t)tok * DIMD + cu * 8);
    }
    int byte = (row * 1024 + cu * 16) ^ ((row & 7) << 4);
    *reinterpret_cast<uint4*>(XsB + byte) = val;
  }
  __syncthreads();

  const unsigned short* w1e = w1t + (size_t)e * HIDN * DIMD;
  const unsigned short* w2e = w2t + (size_t)e * DIMD * HIDN;
  const float* b1e = b1 + e * HIDN;
  const float* b2e = b2 + e * DIMD;

  f32x4 zero = {0.f, 0.f, 0.f, 0.f};
  f32x4 acc[2][8];
  for (int m = 0; m < 2; ++m)
    for (int nf = 0; nf < 8; ++nf) acc[m][nf] = zero;

  int row0 = lane & 15;      // A row (also fragment column index)
  int row1 = row0 + 16;
  int kq = lane >> 4;        // quarter-wave -> k sub-block

  for (int hc = 0; hc < HIDN; hc += HCHK) {
    // GEMM1: this wave computes H[0..32)[wv*32 .. wv*32+32)
    f32x4 hacc[2][2];
    hacc[0][0] = zero; hacc[0][1] = zero; hacc[1][0] = zero; hacc[1][1] = zero;
    int colg = hc + wv * 32 + row0;
#pragma unroll
    for (int kk = 0; kk < 16; ++kk) {
      int kb = kk * 64 + kq * 16;
      bf16x8 a0 = *reinterpret_cast<const bf16x8*>(XsB + ((row0 * 1024 + kb) ^ ((row0 & 7) << 4)));
      bf16x8 a1 = *reinterpret_cast<const bf16x8*>(XsB + ((row1 * 1024 + kb) ^ ((row1 & 7) << 4)));
      int kg = kk * 32 + kq * 8;
      bf16x8 b0  = *reinterpret_cast<const bf16x8*>(w1e + (size_t)colg * DIMD + kg);
      bf16x8 b1f = *reinterpret_cast<const bf16x8*>(w1e + (size_t)(colg + 16) * DIMD + kg);
      hacc[0][0] = __builtin_amdgcn_mfma_f32_16x16x32_bf16(a0, b0,  hacc[0][0], 0, 0, 0);
      hacc[0][1] = __builtin_amdgcn_mfma_f32_16x16x32_bf16(a0, b1f, hacc[0][1], 0, 0, 0);
      hacc[1][0] = __builtin_amdgcn_mfma_f32_16x16x32_bf16(a1, b0,  hacc[1][0], 0, 0, 0);
      hacc[1][1] = __builtin_amdgcn_mfma_f32_16x16x32_bf16(a1, b1f, hacc[1][1], 0, 0, 0);
    }
    __syncthreads();   // prior GEMM2 reads of Hs are done
    // bias + exact gelu, store bf16 H chunk
#pragma unroll
    for (int m = 0; m < 2; ++m) {
#pragma unroll
      for (int nf = 0; nf < 2; ++nf) {
        int cc = wv * 32 + nf * 16 + row0;
        float bias = b1e[hc + cc];
#pragma unroll
        for (int q = 0; q < 4; ++q) {
          int row = m * 16 + kq * 4 + q;
          float v = hacc[m][nf][q] + bias;
          float g = 0.5f * v * (1.f + erff(v * 0.70710678118654752f));
          int byte = (row * 256 + cc * 2) ^ ((row & 7) << 4);
          *reinterpret_cast<unsigned short*>(HsB + byte) = f2bf(g);
        }
      }
    }
    __syncthreads();
    // GEMM2: Y[0..32)[wv*128 ..+128) += Hs @ W2T
#pragma unroll
    for (int kk = 0; kk < 4; ++kk) {
      int kb = kk * 64 + kq * 16;
      bf16x8 ha0 = *reinterpret_cast<const bf16x8*>(HsB + ((row0 * 256 + kb) ^ ((row0 & 7) << 4)));
      bf16x8 ha1 = *reinterpret_cast<const bf16x8*>(HsB + ((row1 * 256 + kb) ^ ((row1 & 7) << 4)));
      int kg = hc + kk * 32 + kq * 8;
#pragma unroll
      for (int nf = 0; nf < 8; ++nf) {
        int col = wv * 128 + nf * 16 + row0;
        bf16x8 bw = *reinterpret_cast<const bf16x8*>(w2e + (size_t)col * HIDN + kg);
        acc[0][nf] = __builtin_amdgcn_mfma_f32_16x16x32_bf16(ha0, bw, acc[0][nf], 0, 0, 0);
        acc[1][nf] = __builtin_amdgcn_mfma_f32_16x16x32_bf16(ha1, bw, acc[1][nf], 0, 0, 0);
      }
    }
  }

  // epilogue: weighted write of Y rows
#pragma unroll
  for (int m = 0; m < 2; ++m) {
#pragma unroll
    for (int q = 0; q < 4; ++q) {
      int row = m * 16 + kq * 4 + q;
      if (row >= nr) continue;
      int a = As[row];
      float w = Wls[row];
      float* yrow = Yw + (size_t)a * DIMD;
#pragma unroll
      for (int nf = 0; nf < 8; ++nf) {
        int col = wv * 128 + nf * 16 + row0;
        yrow[col] = w * (acc[m][nf][q] + b2e[col]);
      }
    }
  }
}

// ---------- combine: out[n] = Yw[2n] + Yw[2n+1] ----------
__global__ __launch_bounds__(256) void combine_kernel(const float* __restrict__ Yw,
                                                      float* __restrict__ out) {
  int i = (blockIdx.x * 256 + threadIdx.x) * 4;
  int n = i >> 9;
  int d = i & 511;
  float4 a = *reinterpret_cast<const float4*>(Yw + (size_t)(2 * n) * DIMD + d);
  float4 b = *reinterpret_cast<const float4*>(Yw + (size_t)(2 * n + 1) * DIMD + d);
  float4 o;
  o.x = a.x + b.x; o.y = a.y + b.y; o.z = a.z + b.z; o.w = a.w + b.w;
  *reinterpret_cast<float4*>(out + i) = o;
}

extern "C" void kernel_launch(void* const* d_in, const int* in_sizes, int n_in,
                              void* d_out, int out_size, void* d_ws, size_t ws_size,
                              hipStream_t stream) {
  const float* x  = (const float*)d_in[0];
  const float* Wr = (const float*)d_in[1];
  const float* br = (const float*)d_in[2];
  const float* W1 = (const float*)d_in[3];
  const float* b1 = (const float*)d_in[4];
  const float* W2 = (const float*)d_in[5];
  const float* b2 = (const float*)d_in[6];
  float* out = (float*)d_out;

  char* ws = (char*)d_ws;
  unsigned short* xb  = (unsigned short*)ws;  ws += (size_t)NTOK * DIMD * 2;
  unsigned short* w1t = (unsigned short*)ws;  ws += (size_t)NEXP * HIDN * DIMD * 2;
  unsigned short* w2t = (unsigned short*)ws;  ws += (size_t)NEXP * DIMD * HIDN * 2;
  float* Yw = (float*)ws;                     ws += (size_t)NASG * DIMD * 4;
  float* tw = (float*)ws;                     ws += (size_t)NASG * 4;
  int* tidx = (int*)ws;                       ws += (size_t)NASG * 4;
  int* list = (int*)ws;                       ws += (size_t)NASG * 4;
  int* ctrl = (int*)ws;                       // cnt[8], cur[8], off[9]
  int* cnt = ctrl;
  int* cur = ctrl + 8;
  int* offp = ctrl + 16;

  hipMemsetAsync(ctrl, 0, 32 * sizeof(int), stream);
  cvt_x_kernel<<<1024, 256, 0, stream>>>(x, xb);
  transpose_w_kernel<<<dim3(HIDN / 64, DIMD / 64, NEXP), 256, 0, stream>>>(W1, w1t, DIMD, HIDN);
  transpose_w_kernel<<<dim3(DIMD / 64, HIDN / 64, NEXP), 256, 0, stream>>>(W2, w2t, HIDN, DIMD);
  router_kernel<<<NTOK / 4, 256, 0, stream>>>(x, Wr, br, cnt, tidx, tw);
  finalize_kernel<<<1, 64, 0, stream>>>(cnt, offp, cur, out + (size_t)NTOK * DIMD);
  scatter_kernel<<<NASG / 256, 256, 0, stream>>>(tidx, offp, cur, list);
  mlp_kernel<<<dim3(NEXP, NTOK / M_BLK), 256, 0, stream>>>(xb, w1t, w2t, b1, b2, offp, list, tw, Yw);
  combine_kernel<<<2048, 256, 0, stream>>>(Yw, out);
}